// Round 4
// baseline (3165.673 us; speedup 1.0000x reference)
//
#include <hip/hip_runtime.h>
#include <math.h>

#define DIM   96
#define QC    24                  /* DIM/4: channels per lane in a 4-lane quad */
#define C4    384
#define STYLE 128
#define LAT   8
#define KK    7
#define BB    2
#define SPD   48
#define SP3   (SPD*SPD*SPD)   /* 110592 */
#define EPSV  1e-6f

/* workspace layout in floats */
#define WS_Z    0                               /* 48: [which3][b2][l8] */
#define WS_WDW  64                              /* 2*96*343 = 65856, [b][c][k] */
#define WS_BDW  (WS_WDW + BB*DIM*343)           /* 192, [b][c] */
#define WS_W1   (WS_BDW + BB*DIM)               /* 2*384*96, [b][o4][c] */
#define WS_B1   (WS_W1 + BB*C4*DIM)             /* 768, [b][o4] */
#define WS_W2T  (WS_B1 + BB*C4)                 /* 2*384*96, [b][c4][o]  (transposed) */
#define WS_B2   (WS_W2T + BB*C4*DIM)            /* 192, [b][o] */
#define WS_H    (WS_B2 + BB*DIM)                /* 2*96*110592, [b][c][sp] */

/* ---------- kernel 1: style -> latent z for the three hyper nets ---------- */
__global__ __launch_bounds__(64) void kz(const float* __restrict__ s,
                                         const float* __restrict__ dwfw, const float* __restrict__ dwfb,
                                         const float* __restrict__ p1fw, const float* __restrict__ p1fb,
                                         const float* __restrict__ p2fw, const float* __restrict__ p2fb,
                                         float* __restrict__ ws) {
    int t = threadIdx.x;
    if (t >= 48) return;
    int which = t >> 4;      /* 0=dw, 1=pw1, 2=pw2 */
    int b = (t >> 3) & 1;
    int l = t & 7;
    const float* fw = (which == 0) ? dwfw : (which == 1) ? p1fw : p2fw;
    const float* fb = (which == 0) ? dwfb : (which == 1) ? p1fb : p2fb;
    float acc = fb[l];
    for (int k = 0; k < STYLE; ++k) acc += s[b*STYLE + k] * fw[l*STYLE + k];
    ws[WS_Z + which*16 + b*8 + l] = acc;
}

/* ---------- kernel 2: latent z -> per-batch conv weights/biases ---------- */
__global__ __launch_bounds__(256) void kw(const float* __restrict__ dwb,  const float* __restrict__ dwbb,
                                          const float* __restrict__ p1b,  const float* __restrict__ p1bb,
                                          const float* __restrict__ p2b,  const float* __restrict__ p2bb,
                                          float* __restrict__ ws) {
    const int n0 = BB*DIM*343;          /* w_dw  */
    const int n1 = n0 + BB*DIM;         /* b_dw  */
    const int n2 = n1 + BB*C4*DIM;      /* w1    */
    const int n3 = n2 + BB*C4;          /* b1    */
    const int n4 = n3 + BB*C4*DIM;      /* w2t   */
    const int n5 = n4 + BB*DIM;         /* b2    */
    int i = blockIdx.x * blockDim.x + threadIdx.x;
    if (i >= n5) return;
    const float* zdw = ws + WS_Z;
    const float* z1  = ws + WS_Z + 16;
    const float* z2  = ws + WS_Z + 32;
    if (i < n0) {
        int b = i / (DIM*343); int r = i % (DIM*343); int c = r / 343; int k = r % 343;
        const float* bank = dwb + ((size_t)(c*343 + k))*LAT;
        const float* z = zdw + b*8;
        float a = 0.f;
        #pragma unroll
        for (int l = 0; l < LAT; ++l) a += bank[l]*z[l];
        ws[WS_WDW + i] = a;
    } else if (i < n1) {
        int j = i - n0; int b = j / DIM; int c = j % DIM;
        const float* z = zdw + b*8;
        float a = 0.f;
        #pragma unroll
        for (int l = 0; l < LAT; ++l) a += dwbb[c*LAT + l]*z[l];
        ws[WS_BDW + j] = a;
    } else if (i < n2) {
        int j = i - n1; int b = j / (C4*DIM); int r = j % (C4*DIM); int o = r / DIM; int c = r % DIM;
        const float* z = z1 + b*8;
        const float* bank = p1b + ((size_t)(o*DIM + c))*LAT;
        float a = 0.f;
        #pragma unroll
        for (int l = 0; l < LAT; ++l) a += bank[l]*z[l];
        ws[WS_W1 + j] = a;
    } else if (i < n3) {
        int j = i - n2; int b = j / C4; int o = j % C4;
        const float* z = z1 + b*8;
        float a = 0.f;
        #pragma unroll
        for (int l = 0; l < LAT; ++l) a += p1bb[o*LAT + l]*z[l];
        ws[WS_B1 + j] = a;
    } else if (i < n4) {
        int j = i - n3; int b = j / (C4*DIM); int r = j % (C4*DIM); int c4 = r / DIM; int o = r % DIM;
        const float* z = z2 + b*8;
        const float* bank = p2b + ((size_t)(o*C4 + c4))*LAT;
        float a = 0.f;
        #pragma unroll
        for (int l = 0; l < LAT; ++l) a += bank[l]*z[l];
        ws[WS_W2T + j] = a;     /* [b][c4][o] */
    } else {
        int j = i - n4; int b = j / DIM; int o = j % DIM;
        const float* z = z2 + b*8;
        float a = 0.f;
        #pragma unroll
        for (int l = 0; l < LAT; ++l) a += p2bb[o*LAT + l]*z[l];
        ws[WS_B2 + j] = a;
    }
}

/* ---------- kernel 3: depthwise 7x7x7 conv (+bias) -> h in ws ---------- */
/* block = 192 threads; per block: one (b,c), output tile 4(z) x 8(y) x 48(x);
   thread computes 8 consecutive x outputs. LDS tile 10 x 14 x 54 (stride 56). */
__global__ __launch_bounds__(192) void kconv(const float* __restrict__ x, float* __restrict__ ws) {
    __shared__ __align__(16) float xt[10*14*56];
    __shared__ __align__(16) float wl[49*8];
    int tid = threadIdx.x;
    int zt = blockIdx.x / 6, yt = blockIdx.x % 6;
    int c = blockIdx.y, b = blockIdx.z;
    int z0 = zt*4, y0 = yt*8;

    if (tid < 343) {
        int r = tid / 7, dx = tid % 7;
        wl[r*8 + dx] = ws[WS_WDW + ((size_t)(b*DIM + c))*343 + tid];
        if (dx == 6) wl[r*8 + 7] = 0.f;
    }
    const float* xsrc = x + ((size_t)(b*DIM + c))*SP3;
    for (int i = tid; i < 10*14*54; i += 192) {
        int iz = i / (14*54); int r = i % (14*54); int iy = r / 54; int ix = r % 54;
        int gz = z0 - 3 + iz, gy = y0 - 3 + iy, gx = ix - 3;
        float v = 0.f;
        if ((unsigned)gz < 48u && (unsigned)gy < 48u && (unsigned)gx < 48u)
            v = xsrc[(gz*SPD + gy)*SPD + gx];
        xt[(iz*14 + iy)*56 + ix] = v;
    }
    __syncthreads();

    int tx = tid % 6; int ty = (tid/6) % 8; int tz = tid / 48;
    int xb = tx*8;
    float acc[8] = {0,0,0,0,0,0,0,0};
    #pragma unroll 1
    for (int dz = 0; dz < 7; ++dz) {
        #pragma unroll 1
        for (int dy = 0; dy < 7; ++dy) {
            const float* row = &xt[((tz+dz)*14 + (ty+dy))*56 + xb];
            float4 r0 = *(const float4*)(row);
            float4 r1 = *(const float4*)(row + 4);
            float4 r2 = *(const float4*)(row + 8);
            float2 r3 = *(const float2*)(row + 12);
            float rr[14] = {r0.x,r0.y,r0.z,r0.w, r1.x,r1.y,r1.z,r1.w,
                            r2.x,r2.y,r2.z,r2.w, r3.x,r3.y};
            const float* wr = &wl[(dz*7 + dy)*8];
            float4 w0 = *(const float4*)(wr);
            float4 w1v = *(const float4*)(wr + 4);
            float wv[7] = {w0.x,w0.y,w0.z,w0.w, w1v.x,w1v.y,w1v.z};
            #pragma unroll
            for (int dx = 0; dx < 7; ++dx)
                #pragma unroll
                for (int j = 0; j < 8; ++j)
                    acc[j] += wv[dx]*rr[dx+j];
        }
    }
    float bias = ws[WS_BDW + b*DIM + c];
    float* hdst = ws + WS_H + ((size_t)(b*DIM + c))*SP3
                + (((z0+tz)*SPD + (y0+ty))*SPD + xb);
    #pragma unroll
    for (int j = 0; j < 8; ++j) hdst[j] = acc[j] + bias;
}

/* ---------- kernel 4: LayerNorm + pw1 + GELU + pw2 + residual ---------- */
/* Lane-QUAD per spatial point: lane p = tid&3 owns channels [24p, 24p+24).
   Per-thread arrays hv[24]+acc[24] = 48 floats + ~30 temps ~= 78 VGPRs,
   which fits UNDER the allocator's observed ~85-VGPR preference (R1/R3 both
   spilled: R3 had hv[48]+acc[48] but VGPR_Count=84 -> 65 GB scratch traffic
   through L2 ~= the whole 2045 us). No min-waves hint: (256,2) NaN'd in R2,
   (256,3) was ignored in R3 — let the allocator have its 6 waves/SIMD.
   Cross-lane coupling: in-quad __shfl_xor 1,2 for LN stats and pw1 dot. */
__global__ __launch_bounds__(256) void kpw(const float* __restrict__ x,
                                           const float* __restrict__ lnw, const float* __restrict__ lnb,
                                           const float* __restrict__ gamma,
                                           float* __restrict__ out, const float* __restrict__ ws) {
    int tid   = threadIdx.x;
    int p     = tid & 3;                        /* channel-quarter index */
    int spi   = (blockIdx.x*256 + tid) >> 2;    /* spatial point (64/block) */
    int b     = blockIdx.y;
    int cbase = p*QC;

    const float* h = ws + WS_H + (size_t)b*DIM*SP3 + (size_t)cbase*SP3 + spi;

    float hv[QC];
    float s = 0.f, q = 0.f;
    #pragma unroll
    for (int i = 0; i < QC; ++i) {
        float v = h[(size_t)i*SP3];
        hv[i] = v; s += v; q += v*v;
    }
    s += __shfl_xor(s, 1);  s += __shfl_xor(s, 2);
    q += __shfl_xor(q, 1);  q += __shfl_xor(q, 2);
    float mean = s * (1.f/96.f);
    float var  = q * (1.f/96.f) - mean*mean;
    float rstd = rsqrtf(fmaxf(var, 0.f) + EPSV);
    #pragma unroll
    for (int i = 0; i < QC; ++i)
        hv[i] = (hv[i] - mean)*rstd*lnw[cbase+i] + lnb[cbase+i];

    float acc[QC];
    const float* b2p = ws + WS_B2 + b*DIM + cbase;
    #pragma unroll
    for (int i = 0; i < QC; ++i) acc[i] = b2p[i];

    const float* w1base = ws + WS_W1  + (size_t)b*C4*DIM + cbase;
    const float* w2base = ws + WS_W2T + (size_t)b*C4*DIM + cbase;
    const float* b1     = ws + WS_B1 + b*C4;
    #pragma unroll 1
    for (int o = 0; o < C4; ++o) {
        const float4* w1r = (const float4*)(w1base + o*DIM);
        float d0 = 0.f, d1 = 0.f, d2 = 0.f, d3 = 0.f;
        #pragma unroll
        for (int i = 0; i < QC/4; ++i) {
            float4 w = w1r[i];
            d0 += w.x*hv[4*i  ];
            d1 += w.y*hv[4*i+1];
            d2 += w.z*hv[4*i+2];
            d3 += w.w*hv[4*i+3];
        }
        float d = (d0+d1) + (d2+d3);
        d += __shfl_xor(d, 1);
        d += __shfl_xor(d, 2);
        float t = d + b1[o];
        float g = 0.5f*t*(1.f + erff(t*0.70710678118f));
        const float4* w2r = (const float4*)(w2base + o*DIM);
        #pragma unroll
        for (int i = 0; i < QC/4; ++i) {
            float4 w = w2r[i];
            acc[4*i  ] += w.x*g;
            acc[4*i+1] += w.y*g;
            acc[4*i+2] += w.z*g;
            acc[4*i+3] += w.w*g;
        }
    }

    size_t xbase = (size_t)b*DIM*SP3 + (size_t)cbase*SP3 + spi;
    #pragma unroll
    for (int i = 0; i < QC; ++i) {
        size_t idx = xbase + (size_t)i*SP3;
        out[idx] = x[idx] + gamma[cbase+i]*acc[i];
    }
}

extern "C" void kernel_launch(void* const* d_in, const int* in_sizes, int n_in,
                              void* d_out, int out_size, void* d_ws, size_t ws_size,
                              hipStream_t stream) {
    const float* x      = (const float*)d_in[0];
    const float* s      = (const float*)d_in[1];
    const float* lnw    = (const float*)d_in[2];
    const float* lnb    = (const float*)d_in[3];
    const float* gamma  = (const float*)d_in[4];
    const float* dwfw   = (const float*)d_in[5];
    const float* dwfb   = (const float*)d_in[6];
    const float* dwbank = (const float*)d_in[7];
    const float* dwbb   = (const float*)d_in[8];
    const float* p1fw   = (const float*)d_in[9];
    const float* p1fb   = (const float*)d_in[10];
    const float* p1bank = (const float*)d_in[11];
    const float* p1bb   = (const float*)d_in[12];
    const float* p2fw   = (const float*)d_in[13];
    const float* p2fb   = (const float*)d_in[14];
    const float* p2bank = (const float*)d_in[15];
    const float* p2bb   = (const float*)d_in[16];
    float* ws  = (float*)d_ws;
    float* out = (float*)d_out;

    kz<<<1, 64, 0, stream>>>(s, dwfw, dwfb, p1fw, p1fb, p2fw, p2fb, ws);
    const int totW = BB*DIM*343 + BB*DIM + BB*C4*DIM + BB*C4 + BB*C4*DIM + BB*DIM;
    kw<<<(totW + 255)/256, 256, 0, stream>>>(dwbank, dwbb, p1bank, p1bb, p2bank, p2bb, ws);
    kconv<<<dim3(72, DIM, BB), 192, 0, stream>>>(x, ws);
    /* 64 spatial points per block (lane quads), SP3/64 = 1728 blocks per batch */
    kpw<<<dim3(SP3/64, BB), 256, 0, stream>>>(x, lnw, lnb, gamma, out, ws);
}

// Round 7
// 1306.368 us; speedup vs baseline: 2.4233x; 2.4233x over previous
//
#include <hip/hip_runtime.h>
#include <math.h>

#define DIM   96
#define C4    384
#define STYLE 128
#define LAT   8
#define KK    7
#define BB    2
#define SPD   48
#define SP3   (SPD*SPD*SPD)   /* 110592 */
#define EPSV  1e-6f

/* workspace layout in floats */
#define WS_Z    0                               /* 48: [which3][b2][l8] */
#define WS_WDW  64                              /* 2*96*343 = 65856, [b][c][k] fp32 */
#define WS_BDW  (WS_WDW + BB*DIM*343)           /* 192, [b][c] fp32 */
#define WS_W1   (WS_BDW + BB*DIM)               /* region holds W1b bf16 [b][384][96] */
#define WS_B1   (WS_W1 + BB*C4*DIM)             /* 768 fp32, [b][o4] */
#define WS_W2T  (WS_B1 + BB*C4)                 /* region holds W2b bf16 [b][96][384] */
#define WS_B2   (WS_W2T + BB*C4*DIM)            /* 192 fp32, [b][o] */
#define WS_H    (WS_B2 + BB*DIM)                /* 2*96*110592 fp32, [b][c][sp] */

typedef __attribute__((ext_vector_type(8))) __bf16 bf16x8;
typedef __attribute__((ext_vector_type(4))) __bf16 bf16x4;
typedef __attribute__((ext_vector_type(4))) float  f32x4;

/* ---------- kernel 1: style -> latent z for the three hyper nets ---------- */
__global__ __launch_bounds__(64) void kz(const float* __restrict__ s,
                                         const float* __restrict__ dwfw, const float* __restrict__ dwfb,
                                         const float* __restrict__ p1fw, const float* __restrict__ p1fb,
                                         const float* __restrict__ p2fw, const float* __restrict__ p2fb,
                                         float* __restrict__ ws) {
    int t = threadIdx.x;
    if (t >= 48) return;
    int which = t >> 4;      /* 0=dw, 1=pw1, 2=pw2 */
    int b = (t >> 3) & 1;
    int l = t & 7;
    const float* fw = (which == 0) ? dwfw : (which == 1) ? p1fw : p2fw;
    const float* fb = (which == 0) ? dwfb : (which == 1) ? p1fb : p2fb;
    float acc = fb[l];
    for (int k = 0; k < STYLE; ++k) acc += s[b*STYLE + k] * fw[l*STYLE + k];
    ws[WS_Z + which*16 + b*8 + l] = acc;
}

/* ---------- kernel 2: latent z -> per-batch conv weights/biases ----------
   dw weights/bias stay fp32 (kconv). pw1/pw2 weights are written as
   ROW-MAJOR BF16: W1b[b][o][c] (384x96), W2b[b][o][c4] (96x384) for direct
   MFMA A-fragment loads. Biases stay fp32. */
__global__ __launch_bounds__(256) void kw(const float* __restrict__ dwb,  const float* __restrict__ dwbb,
                                          const float* __restrict__ p1b,  const float* __restrict__ p1bb,
                                          const float* __restrict__ p2b,  const float* __restrict__ p2bb,
                                          float* __restrict__ ws) {
    const int n0 = BB*DIM*343;          /* w_dw  */
    const int n1 = n0 + BB*DIM;         /* b_dw  */
    const int n2 = n1 + BB*C4*DIM;      /* w1    */
    const int n3 = n2 + BB*C4;          /* b1    */
    const int n4 = n3 + BB*C4*DIM;      /* w2    */
    const int n5 = n4 + BB*DIM;         /* b2    */
    int i = blockIdx.x * blockDim.x + threadIdx.x;
    if (i >= n5) return;
    const float* zdw = ws + WS_Z;
    const float* z1  = ws + WS_Z + 16;
    const float* z2  = ws + WS_Z + 32;
    if (i < n0) {
        int b = i / (DIM*343); int r = i % (DIM*343); int c = r / 343; int k = r % 343;
        const float* bank = dwb + ((size_t)(c*343 + k))*LAT;
        const float* z = zdw + b*8;
        float a = 0.f;
        #pragma unroll
        for (int l = 0; l < LAT; ++l) a += bank[l]*z[l];
        ws[WS_WDW + i] = a;
    } else if (i < n1) {
        int j = i - n0; int b = j / DIM; int c = j % DIM;
        const float* z = zdw + b*8;
        float a = 0.f;
        #pragma unroll
        for (int l = 0; l < LAT; ++l) a += dwbb[c*LAT + l]*z[l];
        ws[WS_BDW + j] = a;
    } else if (i < n2) {
        int j = i - n1; int b = j / (C4*DIM); int r = j % (C4*DIM); int o = r / DIM; int c = r % DIM;
        const float* z = z1 + b*8;
        const float* bank = p1b + ((size_t)(o*DIM + c))*LAT;
        float a = 0.f;
        #pragma unroll
        for (int l = 0; l < LAT; ++l) a += bank[l]*z[l];
        ((__bf16*)(ws + WS_W1))[j] = (__bf16)a;          /* [b][o][c] */
    } else if (i < n3) {
        int j = i - n2; int b = j / C4; int o = j % C4;
        const float* z = z1 + b*8;
        float a = 0.f;
        #pragma unroll
        for (int l = 0; l < LAT; ++l) a += p1bb[o*LAT + l]*z[l];
        ws[WS_B1 + j] = a;
    } else if (i < n4) {
        int j = i - n3; int b = j / (C4*DIM); int r = j % (C4*DIM); int o = r / C4; int c4 = r % C4;
        const float* z = z2 + b*8;
        const float* bank = p2b + ((size_t)(o*C4 + c4))*LAT;
        float a = 0.f;
        #pragma unroll
        for (int l = 0; l < LAT; ++l) a += bank[l]*z[l];
        ((__bf16*)(ws + WS_W2T))[j] = (__bf16)a;         /* [b][o][c4] */
    } else {
        int j = i - n4; int b = j / DIM; int o = j % DIM;
        const float* z = z2 + b*8;
        float a = 0.f;
        #pragma unroll
        for (int l = 0; l < LAT; ++l) a += p2bb[o*LAT + l]*z[l];
        ws[WS_B2 + j] = a;
    }
}

/* ---------- kernel 3: depthwise 7x7x7 conv (+bias) -> h in ws ----------
   R6 ROOT-CAUSE FIX: the old wl staging was `if (tid < 343)` with
   blockDim=192 -> wl entries 224..391 (taps k=192..342) were NEVER
   written — uninitialized-LDS read, UB since R1. First launch saw benign
   fresh LDS; graph replays inherited kpw's 64KB LDS footprint -> junk
   weights -> h blowup -> q=sum(v^2) overflow -> var=inf-inf=NaN in kpw's
   LN -> all-NaN output. Strided loop now covers all 392 entries. */
__global__ __launch_bounds__(192) void kconv(const float* __restrict__ x, float* __restrict__ ws) {
    __shared__ __align__(16) float xt[10*14*56];
    __shared__ __align__(16) float wl[49*8];
    int tid = threadIdx.x;
    int zt = blockIdx.x / 6, yt = blockIdx.x % 6;
    int c = blockIdx.y, b = blockIdx.z;
    int z0 = zt*4, y0 = yt*8;

    const float* wsrc = ws + WS_WDW + ((size_t)(b*DIM + c))*343;
    for (int i = tid; i < 49*8; i += 192) {
        int r = i >> 3, dx = i & 7;
        wl[i] = (dx < 7) ? wsrc[r*7 + dx] : 0.f;
    }
    const float* xsrc = x + ((size_t)(b*DIM + c))*SP3;
    for (int i = tid; i < 10*14*54; i += 192) {
        int iz = i / (14*54); int r = i % (14*54); int iy = r / 54; int ix = r % 54;
        int gz = z0 - 3 + iz, gy = y0 - 3 + iy, gx = ix - 3;
        float v = 0.f;
        if ((unsigned)gz < 48u && (unsigned)gy < 48u && (unsigned)gx < 48u)
            v = xsrc[(gz*SPD + gy)*SPD + gx];
        xt[(iz*14 + iy)*56 + ix] = v;
    }
    __syncthreads();

    int tx = tid % 6; int ty = (tid/6) % 8; int tz = tid / 48;
    int xb = tx*8;
    float acc[8] = {0,0,0,0,0,0,0,0};
    #pragma unroll 1
    for (int dz = 0; dz < 7; ++dz) {
        #pragma unroll 1
        for (int dy = 0; dy < 7; ++dy) {
            const float* row = &xt[((tz+dz)*14 + (ty+dy))*56 + xb];
            float4 r0 = *(const float4*)(row);
            float4 r1 = *(const float4*)(row + 4);
            float4 r2 = *(const float4*)(row + 8);
            float2 r3 = *(const float2*)(row + 12);
            float rr[14] = {r0.x,r0.y,r0.z,r0.w, r1.x,r1.y,r1.z,r1.w,
                            r2.x,r2.y,r2.z,r2.w, r3.x,r3.y};
            const float* wr = &wl[(dz*7 + dy)*8];
            float4 w0 = *(const float4*)(wr);
            float4 w1v = *(const float4*)(wr + 4);
            float wv[7] = {w0.x,w0.y,w0.z,w0.w, w1v.x,w1v.y,w1v.z};
            #pragma unroll
            for (int dx = 0; dx < 7; ++dx)
                #pragma unroll
                for (int j = 0; j < 8; ++j)
                    acc[j] += wv[dx]*rr[dx+j];
        }
    }
    float bias = ws[WS_BDW + b*DIM + c];
    float* hdst = ws + WS_H + ((size_t)(b*DIM + c))*SP3
                + (((z0+tz)*SPD + (y0+ty))*SPD + xb);
    #pragma unroll
    for (int j = 0; j < 8; ++j) hdst[j] = acc[j] + bias;
}

/* ---------- kernel 4: LN + pw1 + GELU + pw2 + residual, MFMA version ----
   Block = 256 threads (4 waves), one batch b, 64 spatial points.
   Accumulators are MFMA f32x4 fragments (nothing to spill — R1/R3/R4
   pathology was the allocator scratch-spilling per-thread arrays).
   LDS = 13312 + 50176 + 2048 = 65536 B -> 2 blocks/CU. */
__global__ __launch_bounds__(256) void kpw(const float* __restrict__ x,
                                           const float* __restrict__ lnw, const float* __restrict__ lnb,
                                           const float* __restrict__ gamma,
                                           float* __restrict__ out, const float* __restrict__ ws) {
    __shared__ __align__(16) __bf16 Hn[64][104];   /* 13312 B */
    __shared__ __align__(16) __bf16 G[64][392];    /* 50176 B */
    __shared__ float2 redbuf[256];                 /*  2048 B */

    const int tid  = threadIdx.x;
    const int lane = tid & 63;
    const int w    = tid >> 6;          /* wave id: Phase-A channel quarter, GEMM N-tile */
    const int b    = blockIdx.y;
    const int sp0  = blockIdx.x * 64;

    /* ---- Phase A: load h, LayerNorm, write bf16 Hn ---- */
    {
        const float* hp = ws + WS_H + (size_t)b*DIM*SP3 + (size_t)(w*24)*SP3 + sp0 + lane;
        float hv[24]; float s = 0.f, q = 0.f;
        #pragma unroll
        for (int i = 0; i < 24; ++i) {
            float v = hp[(size_t)i*SP3];
            hv[i] = v; s += v; q += v*v;
        }
        redbuf[w*64 + lane] = make_float2(s, q);
        __syncthreads();
        float2 r0 = redbuf[lane], r1 = redbuf[64+lane], r2 = redbuf[128+lane], r3 = redbuf[192+lane];
        float st = (r0.x+r1.x) + (r2.x+r3.x);
        float qt = (r0.y+r1.y) + (r2.y+r3.y);
        float mean = st * (1.f/96.f);
        float var  = qt * (1.f/96.f) - mean*mean;
        float rstd = rsqrtf(fmaxf(var, 0.f) + EPSV);
        #pragma unroll
        for (int i = 0; i < 24; ++i) {
            float nv = (hv[i] - mean)*rstd*lnw[w*24+i] + lnb[w*24+i];
            Hn[lane][w*24 + i] = (__bf16)nv;
        }
    }
    __syncthreads();

    const __bf16* W1b = (const __bf16*)(ws + WS_W1)  + (size_t)b*C4*DIM;
    const __bf16* W2b = (const __bf16*)(ws + WS_W2T) + (size_t)b*DIM*C4;
    const float*  b1  = ws + WS_B1 + b*C4;
    const float*  b2  = ws + WS_B2 + b*DIM;

    const int l16  = lane & 15;
    const int quad = lane >> 4;

    /* ---- GEMM1: G[n][o] = gelu(W1 @ Hn + b1), N-tile w ---- */
    {
        const __bf16* bp = &Hn[w*16 + l16][quad*8];
        bf16x8 Bf0 = *(const bf16x8*)(bp);
        bf16x8 Bf1 = *(const bf16x8*)(bp + 32);
        bf16x8 Bf2 = *(const bf16x8*)(bp + 64);

        const __bf16* Arow = W1b + (size_t)l16*DIM + quad*8;
        #pragma unroll 1
        for (int mt = 0; mt < 24; ++mt) {
            const __bf16* ap = Arow + (size_t)mt*16*DIM;
            bf16x8 a0 = *(const bf16x8*)(ap);
            bf16x8 a1 = *(const bf16x8*)(ap + 32);
            bf16x8 a2 = *(const bf16x8*)(ap + 64);
            f32x4 acc = {0.f, 0.f, 0.f, 0.f};
            acc = __builtin_amdgcn_mfma_f32_16x16x32_bf16(a0, Bf0, acc, 0, 0, 0);
            acc = __builtin_amdgcn_mfma_f32_16x16x32_bf16(a1, Bf1, acc, 0, 0, 0);
            acc = __builtin_amdgcn_mfma_f32_16x16x32_bf16(a2, Bf2, acc, 0, 0, 0);
            int obase = mt*16 + quad*4;
            bf16x4 gv;
            #pragma unroll
            for (int r = 0; r < 4; ++r) {
                float t = acc[r] + b1[obase + r];
                float g = 0.5f*t*(1.f + erff(t*0.70710678f));
                gv[r] = (__bf16)g;
            }
            *(bf16x4*)&G[w*16 + l16][obase] = gv;
        }
    }
    __syncthreads();   /* enforce G write->read ordering */

    /* ---- GEMM2: out = x + gamma*(W2 @ G + b2), N-tile w ---- */
    {
        bf16x8 Bg[12];
        const __bf16* gbp = &G[w*16 + l16][quad*8];
        #pragma unroll
        for (int ks = 0; ks < 12; ++ks)
            Bg[ks] = *(const bf16x8*)(gbp + ks*32);

        const __bf16* A2row = W2b + (size_t)l16*C4 + quad*8;
        const int j = w*16 + l16;
        const size_t base = (size_t)b*DIM*SP3 + sp0 + j;
        #pragma unroll 1
        for (int mt = 0; mt < 6; ++mt) {
            const __bf16* ap = A2row + (size_t)mt*16*C4;
            f32x4 acc = {0.f, 0.f, 0.f, 0.f};
            #pragma unroll
            for (int ks = 0; ks < 12; ++ks) {
                bf16x8 a = *(const bf16x8*)(ap + ks*32);
                acc = __builtin_amdgcn_mfma_f32_16x16x32_bf16(a, Bg[ks], acc, 0, 0, 0);
            }
            int obase = mt*16 + quad*4;
            #pragma unroll
            for (int r = 0; r < 4; ++r) {
                int o = obase + r;
                size_t idx = base + (size_t)o*SP3;
                float y = acc[r] + b2[o];
                out[idx] = x[idx] + gamma[o]*y;
            }
        }
    }
}

extern "C" void kernel_launch(void* const* d_in, const int* in_sizes, int n_in,
                              void* d_out, int out_size, void* d_ws, size_t ws_size,
                              hipStream_t stream) {
    const float* x      = (const float*)d_in[0];
    const float* s      = (const float*)d_in[1];
    const float* lnw    = (const float*)d_in[2];
    const float* lnb    = (const float*)d_in[3];
    const float* gamma  = (const float*)d_in[4];
    const float* dwfw   = (const float*)d_in[5];
    const float* dwfb   = (const float*)d_in[6];
    const float* dwbank = (const float*)d_in[7];
    const float* dwbb   = (const float*)d_in[8];
    const float* p1fw   = (const float*)d_in[9];
    const float* p1fb   = (const float*)d_in[10];
    const float* p1bank = (const float*)d_in[11];
    const float* p1bb   = (const float*)d_in[12];
    const float* p2fw   = (const float*)d_in[13];
    const float* p2fb   = (const float*)d_in[14];
    const float* p2bank = (const float*)d_in[15];
    const float* p2bb   = (const float*)d_in[16];
    float* ws  = (float*)d_ws;
    float* out = (float*)d_out;

    kz<<<1, 64, 0, stream>>>(s, dwfw, dwfb, p1fw, p1fb, p2fw, p2fb, ws);
    const int totW = BB*DIM*343 + BB*DIM + BB*C4*DIM + BB*C4 + BB*C4*DIM + BB*DIM;
    kw<<<(totW + 255)/256, 256, 0, stream>>>(dwbank, dwbb, p1bank, p1bb, p2bank, p2bb, ws);
    kconv<<<dim3(72, DIM, BB), 192, 0, stream>>>(x, ws);
    kpw<<<dim3(SP3/64, BB), 256, 0, stream>>>(x, lnw, lnb, gamma, out, ws);
}

// Round 8
// 995.907 us; speedup vs baseline: 3.1787x; 1.3117x over previous
//
#include <hip/hip_runtime.h>
#include <math.h>

#define DIM   96
#define C4    384
#define STYLE 128
#define LAT   8
#define KK    7
#define BB    2
#define SPD   48
#define SP3   (SPD*SPD*SPD)   /* 110592 */
#define EPSV  1e-6f
#define XTS   60              /* xt row stride: NOT ≡0 mod 8 (bank spread), ≡0 mod 4 (b128 align) */

/* workspace layout in floats */
#define WS_Z    0                               /* 48: [which3][b2][l8] */
#define WS_WDW  64                              /* 2*96*343 = 65856, [b][c][k] fp32 */
#define WS_BDW  (WS_WDW + BB*DIM*343)           /* 192, [b][c] fp32 */
#define WS_W1   (WS_BDW + BB*DIM)               /* region holds W1b bf16 [b][384][96] */
#define WS_B1   (WS_W1 + BB*C4*DIM)             /* 768 fp32, [b][o4] */
#define WS_W2T  (WS_B1 + BB*C4)                 /* region holds W2b bf16 [b][96][384] */
#define WS_B2   (WS_W2T + BB*C4*DIM)            /* 192 fp32, [b][o] */
#define WS_H    (WS_B2 + BB*DIM)                /* 2*96*110592 fp32, [b][c][sp] */

typedef __attribute__((ext_vector_type(8))) __bf16 bf16x8;
typedef __attribute__((ext_vector_type(4))) __bf16 bf16x4;
typedef __attribute__((ext_vector_type(4))) float  f32x4;

/* ---------- kernel 1: style -> latent z for the three hyper nets ---------- */
__global__ __launch_bounds__(64) void kz(const float* __restrict__ s,
                                         const float* __restrict__ dwfw, const float* __restrict__ dwfb,
                                         const float* __restrict__ p1fw, const float* __restrict__ p1fb,
                                         const float* __restrict__ p2fw, const float* __restrict__ p2fb,
                                         float* __restrict__ ws) {
    int t = threadIdx.x;
    if (t >= 48) return;
    int which = t >> 4;      /* 0=dw, 1=pw1, 2=pw2 */
    int b = (t >> 3) & 1;
    int l = t & 7;
    const float* fw = (which == 0) ? dwfw : (which == 1) ? p1fw : p2fw;
    const float* fb = (which == 0) ? dwfb : (which == 1) ? p1fb : p2fb;
    float acc = fb[l];
    for (int k = 0; k < STYLE; ++k) acc += s[b*STYLE + k] * fw[l*STYLE + k];
    ws[WS_Z + which*16 + b*8 + l] = acc;
}

/* ---------- kernel 2: latent z -> per-batch conv weights/biases ----------
   dw weights/bias stay fp32 (kconv). pw1/pw2 weights are written as
   ROW-MAJOR BF16: W1b[b][o][c] (384x96), W2b[b][o][c4] (96x384) for direct
   MFMA A-fragment loads. Biases stay fp32. */
__global__ __launch_bounds__(256) void kw(const float* __restrict__ dwb,  const float* __restrict__ dwbb,
                                          const float* __restrict__ p1b,  const float* __restrict__ p1bb,
                                          const float* __restrict__ p2b,  const float* __restrict__ p2bb,
                                          float* __restrict__ ws) {
    const int n0 = BB*DIM*343;          /* w_dw  */
    const int n1 = n0 + BB*DIM;         /* b_dw  */
    const int n2 = n1 + BB*C4*DIM;      /* w1    */
    const int n3 = n2 + BB*C4;          /* b1    */
    const int n4 = n3 + BB*C4*DIM;      /* w2    */
    const int n5 = n4 + BB*DIM;         /* b2    */
    int i = blockIdx.x * blockDim.x + threadIdx.x;
    if (i >= n5) return;
    const float* zdw = ws + WS_Z;
    const float* z1  = ws + WS_Z + 16;
    const float* z2  = ws + WS_Z + 32;
    if (i < n0) {
        int b = i / (DIM*343); int r = i % (DIM*343); int c = r / 343; int k = r % 343;
        const float* bank = dwb + ((size_t)(c*343 + k))*LAT;
        const float* z = zdw + b*8;
        float a = 0.f;
        #pragma unroll
        for (int l = 0; l < LAT; ++l) a += bank[l]*z[l];
        ws[WS_WDW + i] = a;
    } else if (i < n1) {
        int j = i - n0; int b = j / DIM; int c = j % DIM;
        const float* z = zdw + b*8;
        float a = 0.f;
        #pragma unroll
        for (int l = 0; l < LAT; ++l) a += dwbb[c*LAT + l]*z[l];
        ws[WS_BDW + j] = a;
    } else if (i < n2) {
        int j = i - n1; int b = j / (C4*DIM); int r = j % (C4*DIM); int o = r / DIM; int c = r % DIM;
        const float* z = z1 + b*8;
        const float* bank = p1b + ((size_t)(o*DIM + c))*LAT;
        float a = 0.f;
        #pragma unroll
        for (int l = 0; l < LAT; ++l) a += bank[l]*z[l];
        ((__bf16*)(ws + WS_W1))[j] = (__bf16)a;          /* [b][o][c] */
    } else if (i < n3) {
        int j = i - n2; int b = j / C4; int o = j % C4;
        const float* z = z1 + b*8;
        float a = 0.f;
        #pragma unroll
        for (int l = 0; l < LAT; ++l) a += p1bb[o*LAT + l]*z[l];
        ws[WS_B1 + j] = a;
    } else if (i < n4) {
        int j = i - n3; int b = j / (C4*DIM); int r = j % (C4*DIM); int o = r / C4; int c4 = r % C4;
        const float* z = z2 + b*8;
        const float* bank = p2b + ((size_t)(o*C4 + c4))*LAT;
        float a = 0.f;
        #pragma unroll
        for (int l = 0; l < LAT; ++l) a += bank[l]*z[l];
        ((__bf16*)(ws + WS_W2T))[j] = (__bf16)a;         /* [b][o][c4] */
    } else {
        int j = i - n4; int b = j / DIM; int o = j % DIM;
        const float* z = z2 + b*8;
        float a = 0.f;
        #pragma unroll
        for (int l = 0; l < LAT; ++l) a += p2bb[o*LAT + l]*z[l];
        ws[WS_B2 + j] = a;
    }
}

/* ---------- kernel 3: depthwise 7x7x7 conv (+bias) -> h in ws ----------
   R7 fix: xt row stride 56 -> 60 (XTS). With stride 56 (≡0 mod 8) every
   lane's b128 base was ≡0 mod 8 -> all 256 bank-touches/wave-op hit 16 of
   32 banks -> SQ_LDS_BANK_CONFLICT 4.0e8 (~650 µs/CU serialized = 70% of
   the 929 µs kernel). Stride 60 (≡4 mod 8) alternates the mod-8 class per
   row -> all 32 banks used, ~8 touches/bank (ideal). 60≡0 mod 4 keeps the
   16B alignment the b128/b64 reads need. */
__global__ __launch_bounds__(192) void kconv(const float* __restrict__ x, float* __restrict__ ws) {
    __shared__ __align__(16) float xt[10*14*XTS];
    __shared__ __align__(16) float wl[49*8];
    int tid = threadIdx.x;
    int zt = blockIdx.x / 6, yt = blockIdx.x % 6;
    int c = blockIdx.y, b = blockIdx.z;
    int z0 = zt*4, y0 = yt*8;

    const float* wsrc = ws + WS_WDW + ((size_t)(b*DIM + c))*343;
    for (int i = tid; i < 49*8; i += 192) {
        int r = i >> 3, dx = i & 7;
        wl[i] = (dx < 7) ? wsrc[r*7 + dx] : 0.f;
    }
    const float* xsrc = x + ((size_t)(b*DIM + c))*SP3;
    for (int i = tid; i < 10*14*54; i += 192) {
        int iz = i / (14*54); int r = i % (14*54); int iy = r / 54; int ix = r % 54;
        int gz = z0 - 3 + iz, gy = y0 - 3 + iy, gx = ix - 3;
        float v = 0.f;
        if ((unsigned)gz < 48u && (unsigned)gy < 48u && (unsigned)gx < 48u)
            v = xsrc[(gz*SPD + gy)*SPD + gx];
        xt[(iz*14 + iy)*XTS + ix] = v;
    }
    __syncthreads();

    int tx = tid % 6; int ty = (tid/6) % 8; int tz = tid / 48;
    int xb = tx*8;
    float acc[8] = {0,0,0,0,0,0,0,0};
    #pragma unroll 1
    for (int dz = 0; dz < 7; ++dz) {
        #pragma unroll 1
        for (int dy = 0; dy < 7; ++dy) {
            const float* row = &xt[((tz+dz)*14 + (ty+dy))*XTS + xb];
            float4 r0 = *(const float4*)(row);
            float4 r1 = *(const float4*)(row + 4);
            float4 r2 = *(const float4*)(row + 8);
            float2 r3 = *(const float2*)(row + 12);
            float rr[14] = {r0.x,r0.y,r0.z,r0.w, r1.x,r1.y,r1.z,r1.w,
                            r2.x,r2.y,r2.z,r2.w, r3.x,r3.y};
            const float* wr = &wl[(dz*7 + dy)*8];
            float4 w0 = *(const float4*)(wr);
            float4 w1v = *(const float4*)(wr + 4);
            float wv[7] = {w0.x,w0.y,w0.z,w0.w, w1v.x,w1v.y,w1v.z};
            #pragma unroll
            for (int dx = 0; dx < 7; ++dx)
                #pragma unroll
                for (int j = 0; j < 8; ++j)
                    acc[j] += wv[dx]*rr[dx+j];
        }
    }
    float bias = ws[WS_BDW + b*DIM + c];
    float* hdst = ws + WS_H + ((size_t)(b*DIM + c))*SP3
                + (((z0+tz)*SPD + (y0+ty))*SPD + xb);
    #pragma unroll
    for (int j = 0; j < 8; ++j) hdst[j] = acc[j] + bias;
}

/* ---------- kernel 4: LN + pw1 + GELU + pw2 + residual, MFMA version ----
   Block = 256 threads (4 waves), one batch b, 64 spatial points.
   Accumulators are MFMA f32x4 fragments (nothing to spill — R1/R3/R4
   pathology was the allocator scratch-spilling per-thread arrays).
   LDS = 13312 + 50176 + 2048 = 65536 B -> 2 blocks/CU. */
__global__ __launch_bounds__(256) void kpw(const float* __restrict__ x,
                                           const float* __restrict__ lnw, const float* __restrict__ lnb,
                                           const float* __restrict__ gamma,
                                           float* __restrict__ out, const float* __restrict__ ws) {
    __shared__ __align__(16) __bf16 Hn[64][104];   /* 13312 B */
    __shared__ __align__(16) __bf16 G[64][392];    /* 50176 B */
    __shared__ float2 redbuf[256];                 /*  2048 B */

    const int tid  = threadIdx.x;
    const int lane = tid & 63;
    const int w    = tid >> 6;          /* wave id: Phase-A channel quarter, GEMM N-tile */
    const int b    = blockIdx.y;
    const int sp0  = blockIdx.x * 64;

    /* ---- Phase A: load h, LayerNorm, write bf16 Hn ---- */
    {
        const float* hp = ws + WS_H + (size_t)b*DIM*SP3 + (size_t)(w*24)*SP3 + sp0 + lane;
        float hv[24]; float s = 0.f, q = 0.f;
        #pragma unroll
        for (int i = 0; i < 24; ++i) {
            float v = hp[(size_t)i*SP3];
            hv[i] = v; s += v; q += v*v;
        }
        redbuf[w*64 + lane] = make_float2(s, q);
        __syncthreads();
        float2 r0 = redbuf[lane], r1 = redbuf[64+lane], r2 = redbuf[128+lane], r3 = redbuf[192+lane];
        float st = (r0.x+r1.x) + (r2.x+r3.x);
        float qt = (r0.y+r1.y) + (r2.y+r3.y);
        float mean = st * (1.f/96.f);
        float var  = qt * (1.f/96.f) - mean*mean;
        float rstd = rsqrtf(fmaxf(var, 0.f) + EPSV);
        #pragma unroll
        for (int i = 0; i < 24; ++i) {
            float nv = (hv[i] - mean)*rstd*lnw[w*24+i] + lnb[w*24+i];
            Hn[lane][w*24 + i] = (__bf16)nv;
        }
    }
    __syncthreads();

    const __bf16* W1b = (const __bf16*)(ws + WS_W1)  + (size_t)b*C4*DIM;
    const __bf16* W2b = (const __bf16*)(ws + WS_W2T) + (size_t)b*DIM*C4;
    const float*  b1  = ws + WS_B1 + b*C4;
    const float*  b2  = ws + WS_B2 + b*DIM;

    const int l16  = lane & 15;
    const int quad = lane >> 4;

    /* ---- GEMM1: G[n][o] = gelu(W1 @ Hn + b1), N-tile w ---- */
    {
        const __bf16* bp = &Hn[w*16 + l16][quad*8];
        bf16x8 Bf0 = *(const bf16x8*)(bp);
        bf16x8 Bf1 = *(const bf16x8*)(bp + 32);
        bf16x8 Bf2 = *(const bf16x8*)(bp + 64);

        const __bf16* Arow = W1b + (size_t)l16*DIM + quad*8;
        #pragma unroll 1
        for (int mt = 0; mt < 24; ++mt) {
            const __bf16* ap = Arow + (size_t)mt*16*DIM;
            bf16x8 a0 = *(const bf16x8*)(ap);
            bf16x8 a1 = *(const bf16x8*)(ap + 32);
            bf16x8 a2 = *(const bf16x8*)(ap + 64);
            f32x4 acc = {0.f, 0.f, 0.f, 0.f};
            acc = __builtin_amdgcn_mfma_f32_16x16x32_bf16(a0, Bf0, acc, 0, 0, 0);
            acc = __builtin_amdgcn_mfma_f32_16x16x32_bf16(a1, Bf1, acc, 0, 0, 0);
            acc = __builtin_amdgcn_mfma_f32_16x16x32_bf16(a2, Bf2, acc, 0, 0, 0);
            int obase = mt*16 + quad*4;
            bf16x4 gv;
            #pragma unroll
            for (int r = 0; r < 4; ++r) {
                float t = acc[r] + b1[obase + r];
                float g = 0.5f*t*(1.f + erff(t*0.70710678f));
                gv[r] = (__bf16)g;
            }
            *(bf16x4*)&G[w*16 + l16][obase] = gv;
        }
    }
    __syncthreads();   /* enforce G write->read ordering */

    /* ---- GEMM2: out = x + gamma*(W2 @ G + b2), N-tile w ---- */
    {
        bf16x8 Bg[12];
        const __bf16* gbp = &G[w*16 + l16][quad*8];
        #pragma unroll
        for (int ks = 0; ks < 12; ++ks)
            Bg[ks] = *(const bf16x8*)(gbp + ks*32);

        const __bf16* A2row = W2b + (size_t)l16*C4 + quad*8;
        const int j = w*16 + l16;
        const size_t base = (size_t)b*DIM*SP3 + sp0 + j;
        #pragma unroll 1
        for (int mt = 0; mt < 6; ++mt) {
            const __bf16* ap = A2row + (size_t)mt*16*C4;
            f32x4 acc = {0.f, 0.f, 0.f, 0.f};
            #pragma unroll
            for (int ks = 0; ks < 12; ++ks) {
                bf16x8 a = *(const bf16x8*)(ap + ks*32);
                acc = __builtin_amdgcn_mfma_f32_16x16x32_bf16(a, Bg[ks], acc, 0, 0, 0);
            }
            int obase = mt*16 + quad*4;
            #pragma unroll
            for (int r = 0; r < 4; ++r) {
                int o = obase + r;
                size_t idx = base + (size_t)o*SP3;
                float y = acc[r] + b2[o];
                out[idx] = x[idx] + gamma[o]*y;
            }
        }
    }
}

extern "C" void kernel_launch(void* const* d_in, const int* in_sizes, int n_in,
                              void* d_out, int out_size, void* d_ws, size_t ws_size,
                              hipStream_t stream) {
    const float* x      = (const float*)d_in[0];
    const float* s      = (const float*)d_in[1];
    const float* lnw    = (const float*)d_in[2];
    const float* lnb    = (const float*)d_in[3];
    const float* gamma  = (const float*)d_in[4];
    const float* dwfw   = (const float*)d_in[5];
    const float* dwfb   = (const float*)d_in[6];
    const float* dwbank = (const float*)d_in[7];
    const float* dwbb   = (const float*)d_in[8];
    const float* p1fw   = (const float*)d_in[9];
    const float* p1fb   = (const float*)d_in[10];
    const float* p1bank = (const float*)d_in[11];
    const float* p1bb   = (const float*)d_in[12];
    const float* p2fw   = (const float*)d_in[13];
    const float* p2fb   = (const float*)d_in[14];
    const float* p2bank = (const float*)d_in[15];
    const float* p2bb   = (const float*)d_in[16];
    float* ws  = (float*)d_ws;
    float* out = (float*)d_out;

    kz<<<1, 64, 0, stream>>>(s, dwfw, dwfb, p1fw, p1fb, p2fw, p2fb, ws);
    const int totW = BB*DIM*343 + BB*DIM + BB*C4*DIM + BB*C4 + BB*C4*DIM + BB*DIM;
    kw<<<(totW + 255)/256, 256, 0, stream>>>(dwbank, dwbb, p1bank, p1bb, p2bank, p2bb, ws);
    kconv<<<dim3(72, DIM, BB), 192, 0, stream>>>(x, ws);
    kpw<<<dim3(SP3/64, BB), 256, 0, stream>>>(x, lnw, lnb, gamma, out, ws);
}